// Round 2
// baseline (343.583 us; speedup 1.0000x reference)
//
#include <hip/hip_runtime.h>
#include <math.h>

// Problem constants
#define BB_ 2      // batch
#define CC_ 6      // channels
#define NN_ 2048   // points
#define KK_ 64     // keypoints
#define NS_ 32     // neighbors
#define DD_ 32     // feat dim
#define NC_ 216    // candidate grid (6^3)
#define HH_ 64     // hidden dim

// Workspace layout (in floats)
#define OFF_SRC_PACK 0                    // B*N float4 = 16384 floats
#define OFF_TGT_PACK 16384                // 16384
#define OFF_SRC_FEAT 32768                // B*N*D = 131072
#define OFF_TGT_FEAT 163840               // 131072
#define OFF_W        294912               // B*N = 4096
#define OFF_CENTERS  299008               // B*K*3 = 384
#define OFF_XFORM    299392               // 384
#define OFF_SRCDFE   299776               // B*K*D = 4096
#define OFF_SIM      303872               // B*K*NC = 27648
#define OFF_KIDX     331520               // B*K ints = 128
// total ~331648 floats = ~1.33 MB

// -------------------- K1: feature extraction (src + tgt) --------------------
__global__ void fe_kernel(const float* __restrict__ src, const float* __restrict__ tgt,
                          const float* __restrict__ W1, const float* __restrict__ b1,
                          const float* __restrict__ W2, const float* __restrict__ b2,
                          const float* __restrict__ Wwl, const float* __restrict__ bwl,
                          float* __restrict__ ws) {
    int tid = blockIdx.x * blockDim.x + threadIdx.x;
    if (tid >= 2 * BB_ * NN_) return;
    int cloud = tid / (BB_ * NN_);
    int r = tid - cloud * BB_ * NN_;
    int b = r / NN_, n = r % NN_;
    const float* pts = cloud ? tgt : src;
    float x[CC_];
#pragma unroll
    for (int c = 0; c < CC_; ++c) x[c] = pts[(b * CC_ + c) * NN_ + n];
    // packed xyz + squared norm (match numpy sum order: (x^2+y^2)+z^2)
    float bb;
    {
#pragma clang fp contract(off)
        bb = (x[0] * x[0] + x[1] * x[1]) + x[2] * x[2];
    }
    float4* pack = (float4*)(ws + (cloud ? OFF_TGT_PACK : OFF_SRC_PACK));
    pack[b * NN_ + n] = make_float4(x[0], x[1], x[2], bb);

    float h[HH_];
#pragma unroll
    for (int t = 0; t < HH_; ++t) {
        float s = b1[t];
#pragma unroll
        for (int c = 0; c < CC_; ++c) s += x[c] * W1[c * HH_ + t];
        h[t] = fmaxf(s, 0.f);
    }
    float* feat = ws + (cloud ? OFF_TGT_FEAT : OFF_SRC_FEAT) + (size_t)(b * NN_ + n) * DD_;
    float wsum = 0.f;
#pragma unroll 4
    for (int d = 0; d < DD_; ++d) {
        float s = b2[d];
#pragma unroll
        for (int t = 0; t < HH_; ++t) s += h[t] * W2[t * DD_ + d];
        s = fmaxf(s, 0.f);
        feat[d] = s;
        wsum += s * Wwl[d];
    }
    if (cloud == 0) (ws + OFF_W)[b * NN_ + n] = wsum + bwl[0];
}

// -------------------- K2: top-K keypoints + centers + xform --------------------
__global__ void topk_kernel(const float* __restrict__ src, const float* __restrict__ R,
                            const float* __restrict__ t, float* __restrict__ ws,
                            float* __restrict__ out) {
    __shared__ float wv[NN_];
    int b = blockIdx.x;
    int lane = threadIdx.x;
    const float* w = ws + OFF_W + b * NN_;
    for (int j = lane; j < NN_; j += 64) wv[j] = w[j];
    __syncthreads();
    int* kidx = (int*)(ws + OFF_KIDX);
    for (int it = 0; it < KK_; ++it) {
        float bv = -INFINITY;
        int bi = NN_;
        for (int j = lane; j < NN_; j += 64) {
            float v = wv[j];
            if (v > bv) { bv = v; bi = j; }  // increasing j keeps first index on tie
        }
#pragma unroll
        for (int m = 32; m; m >>= 1) {
            float ov = __shfl_xor(bv, m);
            int oi = __shfl_xor(bi, m);
            if (ov > bv || (ov == bv && oi < bi)) { bv = ov; bi = oi; }
        }
        if (lane == 0) {
            kidx[b * KK_ + it] = bi;
            wv[bi] = -INFINITY;
            float c3[3];
#pragma unroll
            for (int c = 0; c < CC_; ++c) {
                float v = src[(b * CC_ + c) * NN_ + bi];
                out[(b * KK_ + it) * CC_ + c] = v;
                if (c < 3) c3[c] = v;
            }
            float* cen = ws + OFF_CENTERS + (b * KK_ + it) * 3;
            cen[0] = c3[0]; cen[1] = c3[1]; cen[2] = c3[2];
            float* xf = ws + OFF_XFORM + (b * KK_ + it) * 3;
#pragma unroll
            for (int i = 0; i < 3; ++i) {
#pragma clang fp contract(off)
                xf[i] = ((R[i * 3 + 0] * c3[0] + R[i * 3 + 1] * c3[1]) + R[i * 3 + 2] * c3[2]) + t[i];
            }
        }
        __syncthreads();
    }
}

// -------------------- K3: src neighbor grouping + dfe + max --------------------
__global__ void src_group_kernel(const float* __restrict__ W3, const float* __restrict__ b3,
                                 const float* __restrict__ W4, const float* __restrict__ b4,
                                 float* __restrict__ ws) {
    __shared__ float d2s[NN_];
    __shared__ float hs[HH_];
    __shared__ float dfe[DD_];
    __shared__ int nns[NS_];
    __shared__ float nnd[NS_];
    int bk = blockIdx.x;
    int b = bk / KK_;
    int lane = threadIdx.x;
    const float* cen = ws + OFF_CENTERS + bk * 3;
    float c0 = cen[0], c1 = cen[1], c2 = cen[2];
    float aa;
    {
#pragma clang fp contract(off)
        aa = (c0 * c0 + c1 * c1) + c2 * c2;
    }
    const float4* pack = (const float4*)(ws + OFF_SRC_PACK) + b * NN_;
    for (int j = lane; j < NN_; j += 64) {
        float4 p = pack[j];
        {
#pragma clang fp contract(off)
            float dot = (c0 * p.x + c1 * p.y) + c2 * p.z;
            d2s[j] = (aa + p.w) - 2.0f * dot;
        }
    }
    if (lane < DD_) dfe[lane] = -INFINITY;
    __syncthreads();
    for (int s = 0; s < NS_; ++s) {
        float bv = INFINITY;
        int bi = NN_;
        for (int j = lane; j < NN_; j += 64) {
            float v = d2s[j];
            if (v < bv) { bv = v; bi = j; }
        }
#pragma unroll
        for (int m = 32; m; m >>= 1) {
            float ov = __shfl_xor(bv, m);
            int oi = __shfl_xor(bi, m);
            if (ov < bv || (ov == bv && oi < bi)) { bv = ov; bi = oi; }
        }
        if (lane == 0) { nns[s] = bi; nnd[s] = bv; d2s[bi] = INFINITY; }
        __syncthreads();
    }
    const float* feats = ws + OFF_SRC_FEAT + (size_t)b * NN_ * DD_;
    for (int s = 0; s < NS_; ++s) {
        int j = (nnd[s] <= 1.0f) ? nns[s] : nns[0];  // RADIUS^2 = 1.0
        float4 p = pack[j];
        float r0 = p.x - c0, r1 = p.y - c1, r2 = p.z - c2;
        const float* f = feats + (size_t)j * DD_;
        float acc = b3[lane] + r0 * W3[0 * HH_ + lane] + r1 * W3[1 * HH_ + lane] + r2 * W3[2 * HH_ + lane];
#pragma unroll 8
        for (int d = 0; d < DD_; ++d) acc += f[d] * W3[(3 + d) * HH_ + lane];
        hs[lane] = fmaxf(acc, 0.f);
        __syncthreads();
        if (lane < DD_) {
            float o = b4[lane];
#pragma unroll 8
            for (int t2 = 0; t2 < HH_; ++t2) o += hs[t2] * W4[t2 * DD_ + lane];
            o = fmaxf(o, 0.f);
            dfe[lane] = fmaxf(dfe[lane], o);
        }
        __syncthreads();
    }
    if (lane < DD_) (ws + OFF_SRCDFE)[bk * DD_ + lane] = dfe[lane];
}

// -------------------- K4: target candidate NN + dfe + sim --------------------
__global__ void tgt_cand_kernel(const float* __restrict__ W3, const float* __restrict__ b3,
                                const float* __restrict__ W4, const float* __restrict__ b4,
                                float* __restrict__ ws) {
    __shared__ float hs[HH_];
    __shared__ float os[DD_];
    int cid = blockIdx.x;
    int b = cid / (KK_ * NC_);
    int rem = cid % (KK_ * NC_);
    int k = rem / NC_;
    int c = rem % NC_;
    int lane = threadIdx.x;
    const float* xf = ws + OFF_XFORM + (b * KK_ + k) * 3;
    int ix = c / 36, iy = (c / 6) % 6, iz = c % 6;
    float cx = xf[0] + (ix * 0.4f - 1.0f);
    float cy = xf[1] + (iy * 0.4f - 1.0f);
    float cz = xf[2] + (iz * 0.4f - 1.0f);
    float aa;
    {
#pragma clang fp contract(off)
        aa = (cx * cx + cy * cy) + cz * cz;
    }
    const float4* pack = (const float4*)(ws + OFF_TGT_PACK) + b * NN_;
    float bv = INFINITY;
    int bi = NN_;
    for (int j = lane; j < NN_; j += 64) {
        float4 p = pack[j];
        float d2;
        {
#pragma clang fp contract(off)
            float dot = (cx * p.x + cy * p.y) + cz * p.z;
            d2 = (aa + p.w) - 2.0f * dot;
        }
        if (d2 < bv) { bv = d2; bi = j; }
    }
#pragma unroll
    for (int m = 32; m; m >>= 1) {
        float ov = __shfl_xor(bv, m);
        int oi = __shfl_xor(bi, m);
        if (ov < bv || (ov == bv && oi < bi)) { bv = ov; bi = oi; }
    }
    // all lanes agree on bi now
    float4 p = pack[bi];
    float r0 = p.x - cx, r1 = p.y - cy, r2 = p.z - cz;
    const float* f = ws + OFF_TGT_FEAT + ((size_t)b * NN_ + bi) * DD_;
    float acc = b3[lane] + r0 * W3[0 * HH_ + lane] + r1 * W3[1 * HH_ + lane] + r2 * W3[2 * HH_ + lane];
#pragma unroll 8
    for (int d = 0; d < DD_; ++d) acc += f[d] * W3[(3 + d) * HH_ + lane];
    hs[lane] = fmaxf(acc, 0.f);
    __syncthreads();
    if (lane < DD_) {
        float o = b4[lane];
#pragma unroll 8
        for (int t2 = 0; t2 < HH_; ++t2) o += hs[t2] * W4[t2 * DD_ + lane];
        o = fmaxf(o, 0.f);
        os[lane] = o * (ws + OFF_SRCDFE)[(b * KK_ + k) * DD_ + lane];
    }
    __syncthreads();
    if (lane == 0) {
        float s = 0.f;
#pragma unroll
        for (int d = 0; d < DD_; ++d) s += os[d];
        (ws + OFF_SIM)[cid] = s;
    }
}

// -------------------- K5: softmax over candidates + vcp --------------------
__global__ void vcp_kernel(float* __restrict__ ws, float* __restrict__ out) {
    int bk = blockIdx.x;
    int lane = threadIdx.x;
    const float* sim = ws + OFF_SIM + bk * NC_;
    const float* xf = ws + OFF_XFORM + bk * 3;
    float m = -INFINITY;
    for (int c = lane; c < NC_; c += 64) m = fmaxf(m, sim[c]);
#pragma unroll
    for (int sh = 32; sh; sh >>= 1) m = fmaxf(m, __shfl_xor(m, sh));
    float se = 0.f, v0 = 0.f, v1 = 0.f, v2 = 0.f;
    for (int c = lane; c < NC_; c += 64) {
        float e = expf(sim[c] - m);
        int ix = c / 36, iy = (c / 6) % 6, iz = c % 6;
        se += e;
        v0 += e * (xf[0] + (ix * 0.4f - 1.0f));
        v1 += e * (xf[1] + (iy * 0.4f - 1.0f));
        v2 += e * (xf[2] + (iz * 0.4f - 1.0f));
    }
#pragma unroll
    for (int sh = 32; sh; sh >>= 1) {
        se += __shfl_xor(se, sh);
        v0 += __shfl_xor(v0, sh);
        v1 += __shfl_xor(v1, sh);
        v2 += __shfl_xor(v2, sh);
    }
    if (lane == 0) {
        float inv = 1.0f / se;
        float* o = out + BB_ * KK_ * CC_ + bk * 3;
        o[0] = v0 * inv;
        o[1] = v1 * inv;
        o[2] = v2 * inv;
    }
}

extern "C" void kernel_launch(void* const* d_in, const int* in_sizes, int n_in,
                              void* d_out, int out_size, void* d_ws, size_t ws_size,
                              hipStream_t stream) {
    const float* src = (const float*)d_in[0];
    const float* tgt = (const float*)d_in[1];
    const float* R   = (const float*)d_in[2];
    const float* t   = (const float*)d_in[3];
    const float* W1  = (const float*)d_in[4];
    const float* b1  = (const float*)d_in[5];
    const float* W2  = (const float*)d_in[6];
    const float* b2  = (const float*)d_in[7];
    const float* Wwl = (const float*)d_in[8];
    const float* bwl = (const float*)d_in[9];
    const float* W3  = (const float*)d_in[10];
    const float* b3  = (const float*)d_in[11];
    const float* W4  = (const float*)d_in[12];
    const float* b4  = (const float*)d_in[13];
    float* ws  = (float*)d_ws;
    float* out = (float*)d_out;

    fe_kernel<<<(2 * BB_ * NN_ + 255) / 256, 256, 0, stream>>>(src, tgt, W1, b1, W2, b2, Wwl, bwl, ws);
    topk_kernel<<<BB_, 64, 0, stream>>>(src, R, t, ws, out);
    src_group_kernel<<<BB_ * KK_, 64, 0, stream>>>(W3, b3, W4, b4, ws);
    tgt_cand_kernel<<<BB_ * KK_ * NC_, 64, 0, stream>>>(W3, b3, W4, b4, ws);
    vcp_kernel<<<BB_ * KK_, 64, 0, stream>>>(ws, out);
}

// Round 3
// 152.152 us; speedup vs baseline: 2.2581x; 2.2581x over previous
//
#include <hip/hip_runtime.h>
#include <math.h>

// Problem constants
#define BB_ 2      // batch
#define CC_ 6      // channels
#define NN_ 2048   // points
#define KK_ 64     // keypoints
#define NS_ 32     // neighbors
#define DD_ 32     // feat dim
#define NC_ 216    // candidate grid (6^3)
#define HH_ 64     // hidden dim

// Workspace layout (in floats)
#define OFF_SRC_PACK 0                    // B*N float4 = 16384 floats
#define OFF_TGT_PACK 16384                // 16384
#define OFF_SRC_FEAT 32768                // B*N*D = 131072
#define OFF_TGT_FEAT 163840               // 131072
#define OFF_W        294912               // B*N = 4096
#define OFF_CENTERS  299008               // B*K*3 = 384
#define OFF_XFORM    299392               // 384
#define OFF_SRCDFE   299776               // B*K*D = 4096
#define OFF_SIM      303872               // B*K*NC = 27648
// total ~331648 floats = ~1.33 MB

// Order-preserving bijection float -> uint32 (ascending)
__device__ __forceinline__ unsigned sortable_f32(float f) {
    unsigned u = __float_as_uint(f);
    return (u & 0x80000000u) ? ~u : (u | 0x80000000u);
}
__device__ __forceinline__ float unsortable_f32(unsigned s) {
    unsigned u = (s & 0x80000000u) ? (s ^ 0x80000000u) : ~s;
    return __uint_as_float(u);
}

// Ascending bitonic sort of N uint64 keys in LDS. N power of 2.
template <int N>
__device__ __forceinline__ void bitonic_sort(unsigned long long* keys, int tid, int nthreads) {
    for (int k = 2; k <= N; k <<= 1) {
        for (int j = k >> 1; j > 0; j >>= 1) {
            __syncthreads();
            for (int p = tid; p < N / 2; p += nthreads) {
                int i = ((p & ~(j - 1)) << 1) | (p & (j - 1));
                int l = i | j;
                unsigned long long a = keys[i], bq = keys[l];
                bool up = ((i & k) == 0);
                if ((a > bq) == up) { keys[i] = bq; keys[l] = a; }
            }
        }
    }
    __syncthreads();
}

// -------------------- K1: feature extraction (src + tgt) --------------------
__global__ void fe_kernel(const float* __restrict__ src, const float* __restrict__ tgt,
                          const float* __restrict__ W1, const float* __restrict__ b1,
                          const float* __restrict__ W2, const float* __restrict__ b2,
                          const float* __restrict__ Wwl, const float* __restrict__ bwl,
                          float* __restrict__ ws) {
    int tid = blockIdx.x * blockDim.x + threadIdx.x;
    if (tid >= 2 * BB_ * NN_) return;
    int cloud = tid / (BB_ * NN_);
    int r = tid - cloud * BB_ * NN_;
    int b = r / NN_, n = r % NN_;
    const float* pts = cloud ? tgt : src;
    float x[CC_];
#pragma unroll
    for (int c = 0; c < CC_; ++c) x[c] = pts[(b * CC_ + c) * NN_ + n];
    float bb;
    {
#pragma clang fp contract(off)
        bb = (x[0] * x[0] + x[1] * x[1]) + x[2] * x[2];
    }
    float4* pack = (float4*)(ws + (cloud ? OFF_TGT_PACK : OFF_SRC_PACK));
    pack[b * NN_ + n] = make_float4(x[0], x[1], x[2], bb);

    float h[HH_];
#pragma unroll
    for (int t = 0; t < HH_; ++t) {
        float s = b1[t];
#pragma unroll
        for (int c = 0; c < CC_; ++c) s += x[c] * W1[c * HH_ + t];
        h[t] = fmaxf(s, 0.f);
    }
    float* feat = ws + (cloud ? OFF_TGT_FEAT : OFF_SRC_FEAT) + (size_t)(b * NN_ + n) * DD_;
    float wsum = 0.f;
#pragma unroll 4
    for (int d = 0; d < DD_; ++d) {
        float s = b2[d];
#pragma unroll
        for (int t = 0; t < HH_; ++t) s += h[t] * W2[t * DD_ + d];
        s = fmaxf(s, 0.f);
        feat[d] = s;
        wsum += s * Wwl[d];
    }
    if (cloud == 0) (ws + OFF_W)[b * NN_ + n] = wsum + bwl[0];
}

// -------------------- K2: top-K keypoints via bitonic sort --------------------
// key = (~sortable(w) << 32) | idx  -> ascending sort == descending by w,
// ties broken by smaller index (jax.lax.top_k semantics).
__global__ void topk_kernel(const float* __restrict__ src, const float* __restrict__ R,
                            const float* __restrict__ t, float* __restrict__ ws,
                            float* __restrict__ out) {
    __shared__ unsigned long long keys[NN_];
    int b = blockIdx.x;
    int tid = threadIdx.x;
    const float* w = ws + OFF_W + b * NN_;
    for (int j = tid; j < NN_; j += blockDim.x)
        keys[j] = ((unsigned long long)(~sortable_f32(w[j])) << 32) | (unsigned)j;
    bitonic_sort<NN_>(keys, tid, blockDim.x);
    if (tid < KK_) {
        int bi = (int)(keys[tid] & 0xFFFFFFFFu);
        float c3[3];
#pragma unroll
        for (int c = 0; c < CC_; ++c) {
            float v = src[(b * CC_ + c) * NN_ + bi];
            out[(b * KK_ + tid) * CC_ + c] = v;
            if (c < 3) c3[c] = v;
        }
        float* cen = ws + OFF_CENTERS + (b * KK_ + tid) * 3;
        cen[0] = c3[0]; cen[1] = c3[1]; cen[2] = c3[2];
        float* xf = ws + OFF_XFORM + (b * KK_ + tid) * 3;
#pragma unroll
        for (int i = 0; i < 3; ++i) {
#pragma clang fp contract(off)
            xf[i] = ((R[i * 3 + 0] * c3[0] + R[i * 3 + 1] * c3[1]) + R[i * 3 + 2] * c3[2]) + t[i];
        }
    }
}

// -------------------- K3: src neighbor grouping + dfe + max --------------------
// 256 threads: bitonic-sort d2 keys (asc, tie -> smaller idx), then 4 wave-groups
// each run 8 of the 32 neighbor MLP steps in parallel.
__global__ void src_group_kernel(const float* __restrict__ W3, const float* __restrict__ b3,
                                 const float* __restrict__ W4, const float* __restrict__ b4,
                                 float* __restrict__ ws) {
    __shared__ unsigned long long keys[NN_];
    __shared__ float hs4[4][HH_];
    __shared__ float dfe4[4][DD_];
    __shared__ int nns[NS_];
    __shared__ float nnd[NS_];
    int bk = blockIdx.x;
    int b = bk / KK_;
    int tid = threadIdx.x;
    int g = tid >> 6, lane = tid & 63;
    const float* cen = ws + OFF_CENTERS + bk * 3;
    float c0 = cen[0], c1 = cen[1], c2 = cen[2];
    float aa;
    {
#pragma clang fp contract(off)
        aa = (c0 * c0 + c1 * c1) + c2 * c2;
    }
    const float4* pack = (const float4*)(ws + OFF_SRC_PACK) + b * NN_;
    for (int j = tid; j < NN_; j += 256) {
#pragma clang fp contract(off)
        float4 p = pack[j];
        float dot = (c0 * p.x + c1 * p.y) + c2 * p.z;
        float d2 = (aa + p.w) - 2.0f * dot;
        keys[j] = ((unsigned long long)sortable_f32(d2) << 32) | (unsigned)j;
    }
    bitonic_sort<NN_>(keys, tid, 256);
    if (tid < NS_) {
        unsigned long long kk = keys[tid];
        nns[tid] = (int)(kk & 0xFFFFFFFFu);
        nnd[tid] = unsortable_f32((unsigned)(kk >> 32));
    }
    __syncthreads();
    const float* feats = ws + OFF_SRC_FEAT + (size_t)b * NN_ * DD_;
    float dmax = -INFINITY;
    for (int it = 0; it < 8; ++it) {
        int s = g * 8 + it;
        int j = (nnd[s] <= 1.0f) ? nns[s] : nns[0];  // RADIUS^2 = 1.0
        float4 p = pack[j];
        float r0 = p.x - c0, r1 = p.y - c1, r2 = p.z - c2;
        const float* f = feats + (size_t)j * DD_;
        float acc = b3[lane] + r0 * W3[0 * HH_ + lane] + r1 * W3[1 * HH_ + lane] + r2 * W3[2 * HH_ + lane];
#pragma unroll 8
        for (int d = 0; d < DD_; ++d) acc += f[d] * W3[(3 + d) * HH_ + lane];
        hs4[g][lane] = fmaxf(acc, 0.f);
        __syncthreads();
        if (lane < DD_) {
            float o = b4[lane];
#pragma unroll 8
            for (int t2 = 0; t2 < HH_; ++t2) o += hs4[g][t2] * W4[t2 * DD_ + lane];
            dmax = fmaxf(dmax, fmaxf(o, 0.f));
        }
        __syncthreads();
    }
    if (lane < DD_) dfe4[g][lane] = dmax;
    __syncthreads();
    if (tid < DD_) {
        float m = fmaxf(fmaxf(dfe4[0][tid], dfe4[1][tid]), fmaxf(dfe4[2][tid], dfe4[3][tid]));
        (ws + OFF_SRCDFE)[bk * DD_ + tid] = m;
    }
}

// -------------------- K4: target candidate NN + dfe + sim --------------------
__global__ void tgt_cand_kernel(const float* __restrict__ W3, const float* __restrict__ b3,
                                const float* __restrict__ W4, const float* __restrict__ b4,
                                float* __restrict__ ws) {
    __shared__ float hs[HH_];
    __shared__ float os[DD_];
    int cid = blockIdx.x;
    int b = cid / (KK_ * NC_);
    int rem = cid % (KK_ * NC_);
    int k = rem / NC_;
    int c = rem % NC_;
    int lane = threadIdx.x;
    const float* xf = ws + OFF_XFORM + (b * KK_ + k) * 3;
    int ix = c / 36, iy = (c / 6) % 6, iz = c % 6;
    float cx = xf[0] + (ix * 0.4f - 1.0f);
    float cy = xf[1] + (iy * 0.4f - 1.0f);
    float cz = xf[2] + (iz * 0.4f - 1.0f);
    float aa;
    {
#pragma clang fp contract(off)
        aa = (cx * cx + cy * cy) + cz * cz;
    }
    const float4* pack = (const float4*)(ws + OFF_TGT_PACK) + b * NN_;
    float bv = INFINITY;
    int bi = NN_;
    for (int j = lane; j < NN_; j += 64) {
        float4 p = pack[j];
        float d2;
        {
#pragma clang fp contract(off)
            float dot = (cx * p.x + cy * p.y) + cz * p.z;
            d2 = (aa + p.w) - 2.0f * dot;
        }
        if (d2 < bv) { bv = d2; bi = j; }
    }
#pragma unroll
    for (int m = 32; m; m >>= 1) {
        float ov = __shfl_xor(bv, m);
        int oi = __shfl_xor(bi, m);
        if (ov < bv || (ov == bv && oi < bi)) { bv = ov; bi = oi; }
    }
    // all lanes agree on bi now
    float4 p = pack[bi];
    float r0 = p.x - cx, r1 = p.y - cy, r2 = p.z - cz;
    const float* f = ws + OFF_TGT_FEAT + ((size_t)b * NN_ + bi) * DD_;
    float acc = b3[lane] + r0 * W3[0 * HH_ + lane] + r1 * W3[1 * HH_ + lane] + r2 * W3[2 * HH_ + lane];
#pragma unroll 8
    for (int d = 0; d < DD_; ++d) acc += f[d] * W3[(3 + d) * HH_ + lane];
    hs[lane] = fmaxf(acc, 0.f);
    __syncthreads();
    if (lane < DD_) {
        float o = b4[lane];
#pragma unroll 8
        for (int t2 = 0; t2 < HH_; ++t2) o += hs[t2] * W4[t2 * DD_ + lane];
        o = fmaxf(o, 0.f);
        os[lane] = o * (ws + OFF_SRCDFE)[(b * KK_ + k) * DD_ + lane];
    }
    __syncthreads();
    if (lane == 0) {
        float s = 0.f;
#pragma unroll
        for (int d = 0; d < DD_; ++d) s += os[d];
        (ws + OFF_SIM)[cid] = s;
    }
}

// -------------------- K5: softmax over candidates + vcp --------------------
__global__ void vcp_kernel(float* __restrict__ ws, float* __restrict__ out) {
    int bk = blockIdx.x;
    int lane = threadIdx.x;
    const float* sim = ws + OFF_SIM + bk * NC_;
    const float* xf = ws + OFF_XFORM + bk * 3;
    float m = -INFINITY;
    for (int c = lane; c < NC_; c += 64) m = fmaxf(m, sim[c]);
#pragma unroll
    for (int sh = 32; sh; sh >>= 1) m = fmaxf(m, __shfl_xor(m, sh));
    float se = 0.f, v0 = 0.f, v1 = 0.f, v2 = 0.f;
    for (int c = lane; c < NC_; c += 64) {
        float e = expf(sim[c] - m);
        int ix = c / 36, iy = (c / 6) % 6, iz = c % 6;
        se += e;
        v0 += e * (xf[0] + (ix * 0.4f - 1.0f));
        v1 += e * (xf[1] + (iy * 0.4f - 1.0f));
        v2 += e * (xf[2] + (iz * 0.4f - 1.0f));
    }
#pragma unroll
    for (int sh = 32; sh; sh >>= 1) {
        se += __shfl_xor(se, sh);
        v0 += __shfl_xor(v0, sh);
        v1 += __shfl_xor(v1, sh);
        v2 += __shfl_xor(v2, sh);
    }
    if (lane == 0) {
        float inv = 1.0f / se;
        float* o = out + BB_ * KK_ * CC_ + bk * 3;
        o[0] = v0 * inv;
        o[1] = v1 * inv;
        o[2] = v2 * inv;
    }
}

extern "C" void kernel_launch(void* const* d_in, const int* in_sizes, int n_in,
                              void* d_out, int out_size, void* d_ws, size_t ws_size,
                              hipStream_t stream) {
    const float* src = (const float*)d_in[0];
    const float* tgt = (const float*)d_in[1];
    const float* R   = (const float*)d_in[2];
    const float* t   = (const float*)d_in[3];
    const float* W1  = (const float*)d_in[4];
    const float* b1  = (const float*)d_in[5];
    const float* W2  = (const float*)d_in[6];
    const float* b2  = (const float*)d_in[7];
    const float* Wwl = (const float*)d_in[8];
    const float* bwl = (const float*)d_in[9];
    const float* W3  = (const float*)d_in[10];
    const float* b3  = (const float*)d_in[11];
    const float* W4  = (const float*)d_in[12];
    const float* b4  = (const float*)d_in[13];
    float* ws  = (float*)d_ws;
    float* out = (float*)d_out;

    fe_kernel<<<(2 * BB_ * NN_ + 255) / 256, 256, 0, stream>>>(src, tgt, W1, b1, W2, b2, Wwl, bwl, ws);
    topk_kernel<<<BB_, 1024, 0, stream>>>(src, R, t, ws, out);
    src_group_kernel<<<BB_ * KK_, 256, 0, stream>>>(W3, b3, W4, b4, ws);
    tgt_cand_kernel<<<BB_ * KK_ * NC_, 64, 0, stream>>>(W3, b3, W4, b4, ws);
    vcp_kernel<<<BB_ * KK_, 64, 0, stream>>>(ws, out);
}

// Round 4
// 122.604 us; speedup vs baseline: 2.8024x; 1.2410x over previous
//
#include <hip/hip_runtime.h>
#include <math.h>

// Problem constants
#define BB_ 2      // batch
#define CC_ 6      // channels
#define NN_ 2048   // points
#define KK_ 64     // keypoints
#define NS_ 32     // neighbors
#define DD_ 32     // feat dim
#define NC_ 216    // candidate grid (6^3)
#define HH_ 64     // hidden dim

// Workspace layout (in floats)
#define OFF_SRC_PACK 0                    // B*N float4 = 16384 floats
#define OFF_TGT_PACK 16384                // 16384
#define OFF_SRC_FEAT 32768                // B*N*D = 131072
#define OFF_TGT_FEAT 163840               // 131072
#define OFF_W        294912               // B*N = 4096
#define OFF_CENTERS  299008               // B*K*3 = 384
#define OFF_XFORM    299392               // 384
#define OFF_SRCDFE   299776               // B*K*D = 4096
#define OFF_SIM      303872               // B*K*NC = 27648
// NNT (27648 ints) aliases the src_feat region: src_feat is dead after src_group_kernel.
#define OFF_NNT      OFF_SRC_FEAT

// Order-preserving bijection float -> uint32 (ascending)
__device__ __forceinline__ unsigned sortable_f32(float f) {
    unsigned u = __float_as_uint(f);
    return (u & 0x80000000u) ? ~u : (u | 0x80000000u);
}
__device__ __forceinline__ float unsortable_f32(unsigned s) {
    unsigned u = (s & 0x80000000u) ? (s ^ 0x80000000u) : ~s;
    return __uint_as_float(u);
}

__device__ __forceinline__ unsigned long long u64min(unsigned long long a, unsigned long long b) {
    return a < b ? a : b;
}

// Full ascending bitonic sort of 64 u64 keys across the 64 lanes of a wave (shfl, no LDS).
__device__ __forceinline__ unsigned long long wave_sort64_asc(unsigned long long key, int lane) {
#pragma unroll
    for (int k = 2; k <= 64; k <<= 1) {
#pragma unroll
        for (int j = k >> 1; j > 0; j >>= 1) {
            unsigned long long other = __shfl_xor(key, j);
            bool lower = (lane & j) == 0;
            bool asc = (lane & k) == 0;
            bool takemin = (lower == asc);
            unsigned long long mn = key < other ? key : other;
            unsigned long long mx = key < other ? other : key;
            key = takemin ? mn : mx;
        }
    }
    return key;
}

// Given two ascending sorted 64-runs (one element per lane), return the smallest 64
// of the union, ascending sorted (one element per lane).
__device__ __forceinline__ unsigned long long merge_keep_min64(unsigned long long a, unsigned long long b, int lane) {
    unsigned long long br = __shfl(b, 63 - lane);       // reverse B
    unsigned long long m = a < br ? a : br;             // bitonic sequence of the 64 smallest
#pragma unroll
    for (int j = 32; j > 0; j >>= 1) {                  // bitonic clean -> ascending
        unsigned long long other = __shfl_xor(m, j);
        bool lower = (lane & j) == 0;
        unsigned long long mn = m < other ? m : other;
        unsigned long long mx = m < other ? other : m;
        m = lower ? mn : mx;
    }
    return m;
}

// Block-level: 1024 threads (16 waves), each thread contributes 2 keys (kA for
// j = w*128+lane, kB for j = w*128+64+lane). Result: runs[0..63] = the 64
// smallest keys of all 2048, ascending. Exact (keys embed unique index).
__device__ __forceinline__ void block_select64(unsigned long long kA, unsigned long long kB,
                                               unsigned long long* runs, int tid) {
    int w = tid >> 6, lane = tid & 63;
    kA = wave_sort64_asc(kA, lane);
    kB = wave_sort64_asc(kB, lane);
    unsigned long long m = merge_keep_min64(kA, kB, lane);
    runs[w * 64 + lane] = m;
    __syncthreads();
#pragma unroll
    for (int lvl = 8; lvl >= 1; lvl >>= 1) {
        unsigned long long r = 0;
        if (w < lvl) {
            unsigned long long a = runs[w * 64 + lane];
            unsigned long long b = runs[(w + lvl) * 64 + lane];
            r = merge_keep_min64(a, b, lane);
        }
        __syncthreads();
        if (w < lvl) runs[w * 64 + lane] = r;
        __syncthreads();
    }
}

// -------------------- K1: feature extraction (src + tgt) --------------------
__global__ void fe_kernel(const float* __restrict__ src, const float* __restrict__ tgt,
                          const float* __restrict__ W1, const float* __restrict__ b1,
                          const float* __restrict__ W2, const float* __restrict__ b2,
                          const float* __restrict__ Wwl, const float* __restrict__ bwl,
                          float* __restrict__ ws) {
    int tid = blockIdx.x * blockDim.x + threadIdx.x;
    if (tid >= 2 * BB_ * NN_) return;
    int cloud = tid / (BB_ * NN_);
    int r = tid - cloud * BB_ * NN_;
    int b = r / NN_, n = r % NN_;
    const float* pts = cloud ? tgt : src;
    float x[CC_];
#pragma unroll
    for (int c = 0; c < CC_; ++c) x[c] = pts[(b * CC_ + c) * NN_ + n];
    float bb;
    {
#pragma clang fp contract(off)
        bb = (x[0] * x[0] + x[1] * x[1]) + x[2] * x[2];
    }
    float4* pack = (float4*)(ws + (cloud ? OFF_TGT_PACK : OFF_SRC_PACK));
    pack[b * NN_ + n] = make_float4(x[0], x[1], x[2], bb);

    float h[HH_];
#pragma unroll
    for (int t = 0; t < HH_; ++t) {
        float s = b1[t];
#pragma unroll
        for (int c = 0; c < CC_; ++c) s += x[c] * W1[c * HH_ + t];
        h[t] = fmaxf(s, 0.f);
    }
    float* feat = ws + (cloud ? OFF_TGT_FEAT : OFF_SRC_FEAT) + (size_t)(b * NN_ + n) * DD_;
    float wsum = 0.f;
#pragma unroll 4
    for (int d = 0; d < DD_; ++d) {
        float s = b2[d];
#pragma unroll
        for (int t = 0; t < HH_; ++t) s += h[t] * W2[t * DD_ + d];
        s = fmaxf(s, 0.f);
        feat[d] = s;
        wsum += s * Wwl[d];
    }
    if (cloud == 0) (ws + OFF_W)[b * NN_ + n] = wsum + bwl[0];
}

// -------------------- K2: top-K keypoints via wave-bitonic selection --------------------
// ascending keys (~sortable(w), idx) == descending by w, ties -> smaller index.
__global__ void topk_kernel(const float* __restrict__ src, const float* __restrict__ R,
                            const float* __restrict__ t, float* __restrict__ ws,
                            float* __restrict__ out) {
    __shared__ unsigned long long runs[16 * 64];
    int b = blockIdx.x;
    int tid = threadIdx.x, w = tid >> 6, lane = tid & 63;
    const float* wv = ws + OFF_W + b * NN_;
    int jA = w * 128 + lane, jB = jA + 64;
    unsigned long long kA = ((unsigned long long)(~sortable_f32(wv[jA])) << 32) | (unsigned)jA;
    unsigned long long kB = ((unsigned long long)(~sortable_f32(wv[jB])) << 32) | (unsigned)jB;
    block_select64(kA, kB, runs, tid);
    if (tid < KK_) {
        int bi = (int)(runs[tid] & 0xFFFFFFFFu);
        float c3[3];
#pragma unroll
        for (int c = 0; c < CC_; ++c) {
            float v = src[(b * CC_ + c) * NN_ + bi];
            out[(b * KK_ + tid) * CC_ + c] = v;
            if (c < 3) c3[c] = v;
        }
        float* cen = ws + OFF_CENTERS + (b * KK_ + tid) * 3;
        cen[0] = c3[0]; cen[1] = c3[1]; cen[2] = c3[2];
        float* xf = ws + OFF_XFORM + (b * KK_ + tid) * 3;
#pragma unroll
        for (int i = 0; i < 3; ++i) {
#pragma clang fp contract(off)
            xf[i] = ((R[i * 3 + 0] * c3[0] + R[i * 3 + 1] * c3[1]) + R[i * 3 + 2] * c3[2]) + t[i];
        }
    }
}

// -------------------- K3: src neighbor grouping + dfe + max --------------------
// 1024 threads: selection of 32 nearest, then 16 waves x 2 neighbors (layer1)
// and 32x32 thread map (layer2).
__global__ void src_group_kernel(const float* __restrict__ W3, const float* __restrict__ b3,
                                 const float* __restrict__ W4, const float* __restrict__ b4,
                                 float* __restrict__ ws) {
    __shared__ unsigned long long runs[16 * 64];
    __shared__ float hs[NS_][HH_];
    __shared__ float outs[NS_][DD_];
    int bk = blockIdx.x;
    int b = bk / KK_;
    int tid = threadIdx.x, w = tid >> 6, lane = tid & 63;
    const float* cen = ws + OFF_CENTERS + bk * 3;
    float c0 = cen[0], c1 = cen[1], c2 = cen[2];
    float aa;
    {
#pragma clang fp contract(off)
        aa = (c0 * c0 + c1 * c1) + c2 * c2;
    }
    float m2x = -2.0f * c0, m2y = -2.0f * c1, m2z = -2.0f * c2;
    const float4* pack = (const float4*)(ws + OFF_SRC_PACK) + b * NN_;
    int jA = w * 128 + lane, jB = jA + 64;
    float4 pA = pack[jA], pB = pack[jB];
    float d2A, d2B;
    {
#pragma clang fp contract(off)
        d2A = (aa + pA.w) + ((m2x * pA.x + m2y * pA.y) + m2z * pA.z);
        d2B = (aa + pB.w) + ((m2x * pB.x + m2y * pB.y) + m2z * pB.z);
    }
    unsigned long long kA = ((unsigned long long)sortable_f32(d2A) << 32) | (unsigned)jA;
    unsigned long long kB = ((unsigned long long)sortable_f32(d2B) << 32) | (unsigned)jB;
    block_select64(kA, kB, runs, tid);
    // layer 1: wave w handles neighbors 2w, 2w+1
    const float* feats = ws + OFF_SRC_FEAT + (size_t)b * NN_ * DD_;
    unsigned long long key0 = runs[0];
#pragma unroll
    for (int ss = 0; ss < 2; ++ss) {
        int s = w * 2 + ss;
        unsigned long long key = runs[s];
        float dd = unsortable_f32((unsigned)(key >> 32));
        int j = (dd <= 1.0f) ? (int)(key & 0xFFFFFFFFu) : (int)(key0 & 0xFFFFFFFFu);  // RADIUS^2=1
        float4 p = pack[j];
        float r0 = p.x - c0, r1 = p.y - c1, r2 = p.z - c2;
        const float* f = feats + (size_t)j * DD_;
        float acc = b3[lane] + r0 * W3[0 * HH_ + lane] + r1 * W3[1 * HH_ + lane] + r2 * W3[2 * HH_ + lane];
#pragma unroll 8
        for (int d = 0; d < DD_; ++d) acc += f[d] * W3[(3 + d) * HH_ + lane];
        hs[s][lane] = fmaxf(acc, 0.f);
    }
    __syncthreads();
    // layer 2: thread = (s = tid>>5, d = tid&31)
    {
        int s2 = tid >> 5, di = tid & 31;
        float o = b4[di];
#pragma unroll 8
        for (int t2 = 0; t2 < HH_; ++t2) o += hs[s2][t2] * W4[t2 * DD_ + di];
        outs[s2][di] = fmaxf(o, 0.f);
    }
    __syncthreads();
    if (tid < DD_) {
        float m = -INFINITY;
#pragma unroll 8
        for (int s = 0; s < NS_; ++s) m = fmaxf(m, outs[s][tid]);
        (ws + OFF_SRCDFE)[bk * DD_ + tid] = m;
    }
}

// -------------------- K4a: candidate NN search (one block per (b,k)) --------------------
__global__ void cand_nn_kernel(float* __restrict__ ws) {
    __shared__ float4 pk[NN_];                 // 32 KB
    __shared__ unsigned long long part[NC_ * 4];  // 6.75 KB
    int bk = blockIdx.x;
    int b = bk / KK_;
    int tid = threadIdx.x;
    const float4* pack = (const float4*)(ws + OFF_TGT_PACK) + b * NN_;
    for (int j = tid; j < NN_; j += 1024) pk[j] = pack[j];
    const float* xf = ws + OFF_XFORM + bk * 3;
    float x0 = xf[0], x1 = xf[1], x2 = xf[2];
    __syncthreads();
    if (tid < NC_ * 4) {
        int cand = tid >> 2, q = tid & 3;
        int ix = cand / 36, iy = (cand / 6) % 6, iz = cand % 6;
        float cx = x0 + (ix * 0.4f - 1.0f);
        float cy = x1 + (iy * 0.4f - 1.0f);
        float cz = x2 + (iz * 0.4f - 1.0f);
        float aa;
        {
#pragma clang fp contract(off)
            aa = (cx * cx + cy * cy) + cz * cz;
        }
        float m2x = -2.0f * cx, m2y = -2.0f * cy, m2z = -2.0f * cz;
        unsigned long long best = ~0ull;
        int base = q * 512;
        for (int i = 0; i < 512; ++i) {
            int j = base + ((i + q) & 511);   // stagger chunk phases -> no LDS bank conflict
            float4 p = pk[j];
            float d2;
            {
#pragma clang fp contract(off)
                d2 = (aa + p.w) + ((m2x * p.x + m2y * p.y) + m2z * p.z);
            }
            unsigned long long key = ((unsigned long long)sortable_f32(d2) << 32) | (unsigned)j;
            best = key < best ? key : best;
        }
        part[tid] = best;
    }
    __syncthreads();
    if (tid < NC_) {
        unsigned long long mm = u64min(u64min(part[tid * 4], part[tid * 4 + 1]),
                                       u64min(part[tid * 4 + 2], part[tid * 4 + 3]));
        ((int*)ws)[OFF_NNT + bk * NC_ + tid] = (int)(mm & 0xFFFFFFFFu);
    }
}

// -------------------- K4b: per-candidate MLP + sim (thread per candidate) --------------------
__global__ void mlp_sim_kernel(const float* __restrict__ W3, const float* __restrict__ b3,
                               const float* __restrict__ W4, const float* __restrict__ b4,
                               float* __restrict__ ws) {
    int cid = blockIdx.x * 256 + threadIdx.x;
    int b = cid / (KK_ * NC_);
    int rem = cid % (KK_ * NC_);
    int k = rem / NC_;
    int c = rem % NC_;
    const float* xf = ws + OFF_XFORM + (b * KK_ + k) * 3;
    int ix = c / 36, iy = (c / 6) % 6, iz = c % 6;
    float cx = xf[0] + (ix * 0.4f - 1.0f);
    float cy = xf[1] + (iy * 0.4f - 1.0f);
    float cz = xf[2] + (iz * 0.4f - 1.0f);
    int bi = ((const int*)ws)[OFF_NNT + (b * KK_ + k) * NC_ + c];
    float4 p = ((const float4*)(ws + OFF_TGT_PACK))[b * NN_ + bi];
    float x[3 + DD_];
    x[0] = p.x - cx; x[1] = p.y - cy; x[2] = p.z - cz;
    const float* f = ws + OFF_TGT_FEAT + ((size_t)b * NN_ + bi) * DD_;
#pragma unroll
    for (int d = 0; d < DD_; ++d) x[3 + d] = f[d];
    float out[DD_];
#pragma unroll
    for (int d = 0; d < DD_; ++d) out[d] = b4[d];
    for (int t = 0; t < HH_; ++t) {
        float acc = b3[t];
#pragma unroll
        for (int cc = 0; cc < 3 + DD_; ++cc) acc += x[cc] * W3[cc * HH_ + t];
        float ht = fmaxf(acc, 0.f);
#pragma unroll
        for (int d = 0; d < DD_; ++d) out[d] += ht * W4[t * DD_ + d];
    }
    const float* sd = ws + OFF_SRCDFE + (b * KK_ + k) * DD_;
    float sim = 0.f;
#pragma unroll
    for (int d = 0; d < DD_; ++d) sim += fmaxf(out[d], 0.f) * sd[d];
    (ws + OFF_SIM)[cid] = sim;
}

// -------------------- K5: softmax over candidates + vcp --------------------
__global__ void vcp_kernel(float* __restrict__ ws, float* __restrict__ out) {
    int bk = blockIdx.x;
    int lane = threadIdx.x;
    const float* sim = ws + OFF_SIM + bk * NC_;
    const float* xf = ws + OFF_XFORM + bk * 3;
    float m = -INFINITY;
    for (int c = lane; c < NC_; c += 64) m = fmaxf(m, sim[c]);
#pragma unroll
    for (int sh = 32; sh; sh >>= 1) m = fmaxf(m, __shfl_xor(m, sh));
    float se = 0.f, v0 = 0.f, v1 = 0.f, v2 = 0.f;
    for (int c = lane; c < NC_; c += 64) {
        float e = expf(sim[c] - m);
        int ix = c / 36, iy = (c / 6) % 6, iz = c % 6;
        se += e;
        v0 += e * (xf[0] + (ix * 0.4f - 1.0f));
        v1 += e * (xf[1] + (iy * 0.4f - 1.0f));
        v2 += e * (xf[2] + (iz * 0.4f - 1.0f));
    }
#pragma unroll
    for (int sh = 32; sh; sh >>= 1) {
        se += __shfl_xor(se, sh);
        v0 += __shfl_xor(v0, sh);
        v1 += __shfl_xor(v1, sh);
        v2 += __shfl_xor(v2, sh);
    }
    if (lane == 0) {
        float inv = 1.0f / se;
        float* o = out + BB_ * KK_ * CC_ + bk * 3;
        o[0] = v0 * inv;
        o[1] = v1 * inv;
        o[2] = v2 * inv;
    }
}

extern "C" void kernel_launch(void* const* d_in, const int* in_sizes, int n_in,
                              void* d_out, int out_size, void* d_ws, size_t ws_size,
                              hipStream_t stream) {
    const float* src = (const float*)d_in[0];
    const float* tgt = (const float*)d_in[1];
    const float* R   = (const float*)d_in[2];
    const float* t   = (const float*)d_in[3];
    const float* W1  = (const float*)d_in[4];
    const float* b1  = (const float*)d_in[5];
    const float* W2  = (const float*)d_in[6];
    const float* b2  = (const float*)d_in[7];
    const float* Wwl = (const float*)d_in[8];
    const float* bwl = (const float*)d_in[9];
    const float* W3  = (const float*)d_in[10];
    const float* b3  = (const float*)d_in[11];
    const float* W4  = (const float*)d_in[12];
    const float* b4  = (const float*)d_in[13];
    float* ws  = (float*)d_ws;
    float* out = (float*)d_out;

    fe_kernel<<<(2 * BB_ * NN_ + 255) / 256, 256, 0, stream>>>(src, tgt, W1, b1, W2, b2, Wwl, bwl, ws);
    topk_kernel<<<BB_, 1024, 0, stream>>>(src, R, t, ws, out);
    src_group_kernel<<<BB_ * KK_, 1024, 0, stream>>>(W3, b3, W4, b4, ws);
    cand_nn_kernel<<<BB_ * KK_, 1024, 0, stream>>>(ws);
    mlp_sim_kernel<<<(BB_ * KK_ * NC_) / 256, 256, 0, stream>>>(W3, b3, W4, b4, ws);
    vcp_kernel<<<BB_ * KK_, 64, 0, stream>>>(ws, out);
}

// Round 5
// 88.923 us; speedup vs baseline: 3.8638x; 1.3788x over previous
//
#include <hip/hip_runtime.h>
#include <math.h>

// Problem constants
#define BB_ 2      // batch
#define CC_ 6      // channels
#define NN_ 2048   // points
#define KK_ 64     // keypoints
#define NS_ 32     // neighbors
#define DD_ 32     // feat dim
#define NC_ 216    // candidate grid (6^3)
#define HH_ 64     // hidden dim

// Workspace layout (in floats)
#define OFF_SRC_PACK 0                    // B*N float4 = 16384 floats
#define OFF_TGT_PACK 16384                // 16384
#define OFF_SRC_FEAT 32768                // B*N*D = 131072
#define OFF_TGT_FEAT 163840               // 131072
#define OFF_W        294912               // B*N = 4096
#define OFF_CENTERS  299008               // B*K*3 = 384
#define OFF_XFORM    299392               // 384
#define OFF_SRCDFE   299776               // B*K*D = 4096
// NNT (27648 ints) aliases the src_feat region: src_feat is dead after src_group_kernel
// (cand_nn launches after src_group on the same stream).
#define OFF_NNT      OFF_SRC_FEAT

// Order-preserving bijection float -> uint32 (ascending)
__device__ __forceinline__ unsigned sortable_f32(float f) {
    unsigned u = __float_as_uint(f);
    return (u & 0x80000000u) ? ~u : (u | 0x80000000u);
}
__device__ __forceinline__ float unsortable_f32(unsigned s) {
    unsigned u = (s & 0x80000000u) ? (s ^ 0x80000000u) : ~s;
    return __uint_as_float(u);
}

// Full ascending bitonic sort of 64 u64 keys across the 64 lanes of a wave (shfl, no LDS).
__device__ __forceinline__ unsigned long long wave_sort64_asc(unsigned long long key, int lane) {
#pragma unroll
    for (int k = 2; k <= 64; k <<= 1) {
#pragma unroll
        for (int j = k >> 1; j > 0; j >>= 1) {
            unsigned long long other = __shfl_xor(key, j);
            bool lower = (lane & j) == 0;
            bool asc = (lane & k) == 0;
            bool takemin = (lower == asc);
            unsigned long long mn = key < other ? key : other;
            unsigned long long mx = key < other ? other : key;
            key = takemin ? mn : mx;
        }
    }
    return key;
}

// Two ascending sorted 64-runs -> smallest 64 of the union, ascending.
__device__ __forceinline__ unsigned long long merge_keep_min64(unsigned long long a, unsigned long long b, int lane) {
    unsigned long long br = __shfl(b, 63 - lane);
    unsigned long long m = a < br ? a : br;
#pragma unroll
    for (int j = 32; j > 0; j >>= 1) {
        unsigned long long other = __shfl_xor(m, j);
        bool lower = (lane & j) == 0;
        unsigned long long mn = m < other ? m : other;
        unsigned long long mx = m < other ? other : m;
        m = lower ? mn : mx;
    }
    return m;
}

// 1024 threads (16 waves), 2 keys per thread -> runs[0..63] = 64 smallest, ascending.
__device__ __forceinline__ void block_select64(unsigned long long kA, unsigned long long kB,
                                               unsigned long long* runs, int tid) {
    int w = tid >> 6, lane = tid & 63;
    kA = wave_sort64_asc(kA, lane);
    kB = wave_sort64_asc(kB, lane);
    unsigned long long m = merge_keep_min64(kA, kB, lane);
    runs[w * 64 + lane] = m;
    __syncthreads();
#pragma unroll
    for (int lvl = 8; lvl >= 1; lvl >>= 1) {
        unsigned long long r = 0;
        if (w < lvl) {
            unsigned long long a = runs[w * 64 + lane];
            unsigned long long b = runs[(w + lvl) * 64 + lane];
            r = merge_keep_min64(a, b, lane);
        }
        __syncthreads();
        if (w < lvl) runs[w * 64 + lane] = r;
        __syncthreads();
    }
}

// -------------------- K1: feature extraction (src + tgt) --------------------
__global__ void fe_kernel(const float* __restrict__ src, const float* __restrict__ tgt,
                          const float* __restrict__ W1, const float* __restrict__ b1,
                          const float* __restrict__ W2, const float* __restrict__ b2,
                          const float* __restrict__ Wwl, const float* __restrict__ bwl,
                          float* __restrict__ ws) {
    int tid = blockIdx.x * blockDim.x + threadIdx.x;
    if (tid >= 2 * BB_ * NN_) return;
    int cloud = tid / (BB_ * NN_);
    int r = tid - cloud * BB_ * NN_;
    int b = r / NN_, n = r % NN_;
    const float* pts = cloud ? tgt : src;
    float x[CC_];
#pragma unroll
    for (int c = 0; c < CC_; ++c) x[c] = pts[(b * CC_ + c) * NN_ + n];
    float bb;
    {
#pragma clang fp contract(off)
        bb = (x[0] * x[0] + x[1] * x[1]) + x[2] * x[2];
    }
    float4* pack = (float4*)(ws + (cloud ? OFF_TGT_PACK : OFF_SRC_PACK));
    pack[b * NN_ + n] = make_float4(x[0], x[1], x[2], bb);

    float h[HH_];
#pragma unroll
    for (int t = 0; t < HH_; ++t) {
        float s = b1[t];
#pragma unroll
        for (int c = 0; c < CC_; ++c) s += x[c] * W1[c * HH_ + t];
        h[t] = fmaxf(s, 0.f);
    }
    float* feat = ws + (cloud ? OFF_TGT_FEAT : OFF_SRC_FEAT) + (size_t)(b * NN_ + n) * DD_;
    float wsum = 0.f;
#pragma unroll 4
    for (int d = 0; d < DD_; ++d) {
        float s = b2[d];
#pragma unroll
        for (int t = 0; t < HH_; ++t) s += h[t] * W2[t * DD_ + d];
        s = fmaxf(s, 0.f);
        feat[d] = s;
        wsum += s * Wwl[d];
    }
    if (cloud == 0) (ws + OFF_W)[b * NN_ + n] = wsum + bwl[0];
}

// -------------------- K2: top-K keypoints via wave-bitonic selection --------------------
__global__ void topk_kernel(const float* __restrict__ src, const float* __restrict__ R,
                            const float* __restrict__ t, float* __restrict__ ws,
                            float* __restrict__ out) {
    __shared__ unsigned long long runs[16 * 64];
    int b = blockIdx.x;
    int tid = threadIdx.x, w = tid >> 6, lane = tid & 63;
    const float* wv = ws + OFF_W + b * NN_;
    int jA = w * 128 + lane, jB = jA + 64;
    unsigned long long kA = ((unsigned long long)(~sortable_f32(wv[jA])) << 32) | (unsigned)jA;
    unsigned long long kB = ((unsigned long long)(~sortable_f32(wv[jB])) << 32) | (unsigned)jB;
    block_select64(kA, kB, runs, tid);
    if (tid < KK_) {
        int bi = (int)(runs[tid] & 0xFFFFFFFFu);
        float c3[3];
#pragma unroll
        for (int c = 0; c < CC_; ++c) {
            float v = src[(b * CC_ + c) * NN_ + bi];
            out[(b * KK_ + tid) * CC_ + c] = v;
            if (c < 3) c3[c] = v;
        }
        float* cen = ws + OFF_CENTERS + (b * KK_ + tid) * 3;
        cen[0] = c3[0]; cen[1] = c3[1]; cen[2] = c3[2];
        float* xf = ws + OFF_XFORM + (b * KK_ + tid) * 3;
#pragma unroll
        for (int i = 0; i < 3; ++i) {
#pragma clang fp contract(off)
            xf[i] = ((R[i * 3 + 0] * c3[0] + R[i * 3 + 1] * c3[1]) + R[i * 3 + 2] * c3[2]) + t[i];
        }
    }
}

// -------------------- K3: src neighbor grouping + dfe + max --------------------
__global__ void src_group_kernel(const float* __restrict__ W3, const float* __restrict__ b3,
                                 const float* __restrict__ W4, const float* __restrict__ b4,
                                 float* __restrict__ ws) {
    __shared__ unsigned long long runs[16 * 64];
    __shared__ float hs[NS_][HH_];
    __shared__ float outs[NS_][DD_];
    int bk = blockIdx.x;
    int b = bk / KK_;
    int tid = threadIdx.x, w = tid >> 6, lane = tid & 63;
    const float* cen = ws + OFF_CENTERS + bk * 3;
    float c0 = cen[0], c1 = cen[1], c2 = cen[2];
    float aa;
    {
#pragma clang fp contract(off)
        aa = (c0 * c0 + c1 * c1) + c2 * c2;
    }
    float m2x = -2.0f * c0, m2y = -2.0f * c1, m2z = -2.0f * c2;
    const float4* pack = (const float4*)(ws + OFF_SRC_PACK) + b * NN_;
    int jA = w * 128 + lane, jB = jA + 64;
    float4 pA = pack[jA], pB = pack[jB];
    float d2A, d2B;
    {
#pragma clang fp contract(off)
        d2A = (aa + pA.w) + ((m2x * pA.x + m2y * pA.y) + m2z * pA.z);
        d2B = (aa + pB.w) + ((m2x * pB.x + m2y * pB.y) + m2z * pB.z);
    }
    unsigned long long kA = ((unsigned long long)sortable_f32(d2A) << 32) | (unsigned)jA;
    unsigned long long kB = ((unsigned long long)sortable_f32(d2B) << 32) | (unsigned)jB;
    block_select64(kA, kB, runs, tid);
    const float* feats = ws + OFF_SRC_FEAT + (size_t)b * NN_ * DD_;
    unsigned long long key0 = runs[0];
#pragma unroll
    for (int ss = 0; ss < 2; ++ss) {
        int s = w * 2 + ss;
        unsigned long long key = runs[s];
        float dd = unsortable_f32((unsigned)(key >> 32));
        int j = (dd <= 1.0f) ? (int)(key & 0xFFFFFFFFu) : (int)(key0 & 0xFFFFFFFFu);  // RADIUS^2=1
        float4 p = pack[j];
        float r0 = p.x - c0, r1 = p.y - c1, r2 = p.z - c2;
        const float* f = feats + (size_t)j * DD_;
        float acc = b3[lane] + r0 * W3[0 * HH_ + lane] + r1 * W3[1 * HH_ + lane] + r2 * W3[2 * HH_ + lane];
#pragma unroll 8
        for (int d = 0; d < DD_; ++d) acc += f[d] * W3[(3 + d) * HH_ + lane];
        hs[s][lane] = fmaxf(acc, 0.f);
    }
    __syncthreads();
    {
        int s2 = tid >> 5, di = tid & 31;
        float o = b4[di];
#pragma unroll 8
        for (int t2 = 0; t2 < HH_; ++t2) o += hs[s2][t2] * W4[t2 * DD_ + di];
        outs[s2][di] = fmaxf(o, 0.f);
    }
    __syncthreads();
    if (tid < DD_) {
        float m = -INFINITY;
#pragma unroll 8
        for (int s = 0; s < NS_; ++s) m = fmaxf(m, outs[s][tid]);
        (ws + OFF_SRCDFE)[bk * DD_ + tid] = m;
    }
}

// -------------------- K4a: candidate NN search v2 --------------------
// Grid: 256 blocks = (bk, candidate-half). Block: 576 threads = 18 groups x 32 chunks.
// Group g handles the 6 candidates sharing (ix,iy) = (g/6, g%6); per point, txy is
// shared across the 6. d2 is bit-identical to the reference by the power-of-2
// scaling lemma. Ascending-j scan + strict < keeps first index; cross-chunk merge
// via u64 (sortable(d2)<<32|j) shfl-xor min tree.
__global__ void cand_nn_kernel(float* __restrict__ ws) {
    __shared__ float4 pk[NN_];                 // 32 KB, XOR-swizzled slots
    int blk = blockIdx.x;
    int bk = blk >> 1;
    int half = blk & 1;
    int b = bk / KK_;
    int tid = threadIdx.x;                     // 0..575
    const float4* pack = (const float4*)(ws + OFF_TGT_PACK) + b * NN_;
    for (int j = tid; j < NN_; j += 576) {
        pk[j ^ ((j >> 6) & 7)] = pack[j];
    }
    const float* xf = ws + OFF_XFORM + bk * 3;
    float x0 = xf[0], x1 = xf[1], x2 = xf[2];
    __syncthreads();

    int lg = tid >> 5;                         // local group 0..17
    int chunk = tid & 31;
    int grp = half * 18 + lg;                  // 0..35 = ix*6+iy
    int ix = grp / 6, iy = grp % 6;
    float cx = x0 + (ix * 0.4f - 1.0f);
    float cy = x1 + (iy * 0.4f - 1.0f);
    float cxy2;
    {
#pragma clang fp contract(off)
        cxy2 = cx * cx + cy * cy;
    }
    float m2x = -2.0f * cx, m2y = -2.0f * cy;
    float aaz[6], m2z[6];
#pragma unroll
    for (int z = 0; z < 6; ++z) {
        float cz = x2 + (z * 0.4f - 1.0f);
        {
#pragma clang fp contract(off)
            aaz[z] = cxy2 + cz * cz;
        }
        m2z[z] = -2.0f * cz;
    }
    float bv[6];
    int bi[6];
#pragma unroll
    for (int z = 0; z < 6; ++z) { bv[z] = INFINITY; bi[z] = 0; }
    int base = chunk * 64;
    int sw = chunk & 7;
    for (int i = 0; i < 64; ++i) {
        int j = base + i;                      // ascending j
        float4 p = pk[base + (i ^ sw)];        // swizzled slot of point j? no:
        // NOTE: slot(j) = j ^ ((j>>6)&7) = base + (i ^ sw) -> this IS point j.
        float txy;
        {
#pragma clang fp contract(off)
            txy = m2x * p.x + m2y * p.y;
        }
#pragma unroll
        for (int z = 0; z < 6; ++z) {
            float d2;
            {
#pragma clang fp contract(off)
                d2 = (aaz[z] + p.w) + (txy + m2z[z] * p.z);
            }
            if (d2 < bv[z]) { bv[z] = d2; bi[z] = j; }
        }
    }
    int* nnt = (int*)ws + OFF_NNT + bk * NC_ + grp * 6;
#pragma unroll
    for (int z = 0; z < 6; ++z) {
        unsigned long long key = ((unsigned long long)sortable_f32(bv[z]) << 32) | (unsigned)bi[z];
#pragma unroll
        for (int m = 1; m <= 16; m <<= 1) {
            unsigned long long other = __shfl_xor(key, m);
            key = other < key ? other : key;
        }
        if (chunk == 0) nnt[z] = (int)(key & 0xFFFFFFFFu);
    }
}

// -------------------- K4b: per-candidate MLP + sim + softmax + vcp (fused) ----
// One block per (b,k), 256 threads; threads 0..215 each handle one candidate.
__global__ void simvcp_kernel(const float* __restrict__ W3, const float* __restrict__ b3,
                              const float* __restrict__ W4, const float* __restrict__ b4,
                              float* __restrict__ ws, float* __restrict__ out) {
    __shared__ float sims[NC_];
    int bk = blockIdx.x;
    int b = bk / KK_;
    int tid = threadIdx.x;
    const float* xf = ws + OFF_XFORM + bk * 3;
    if (tid < NC_) {
        int c = tid;
        int ix = c / 36, iy = (c / 6) % 6, iz = c % 6;
        float cx = xf[0] + (ix * 0.4f - 1.0f);
        float cy = xf[1] + (iy * 0.4f - 1.0f);
        float cz = xf[2] + (iz * 0.4f - 1.0f);
        int bi = ((const int*)ws)[OFF_NNT + bk * NC_ + c];
        float4 p = ((const float4*)(ws + OFF_TGT_PACK))[b * NN_ + bi];
        float x[3 + DD_];
        x[0] = p.x - cx; x[1] = p.y - cy; x[2] = p.z - cz;
        const float* f = ws + OFF_TGT_FEAT + ((size_t)b * NN_ + bi) * DD_;
#pragma unroll
        for (int d = 0; d < DD_; ++d) x[3 + d] = f[d];
        float o[DD_];
#pragma unroll
        for (int d = 0; d < DD_; ++d) o[d] = b4[d];
        for (int t = 0; t < HH_; ++t) {
            float acc = b3[t];
#pragma unroll
            for (int cc = 0; cc < 3 + DD_; ++cc) acc += x[cc] * W3[cc * HH_ + t];
            float ht = fmaxf(acc, 0.f);
#pragma unroll
            for (int d = 0; d < DD_; ++d) o[d] += ht * W4[t * DD_ + d];
        }
        const float* sd = ws + OFF_SRCDFE + bk * DD_;
        float sim = 0.f;
#pragma unroll
        for (int d = 0; d < DD_; ++d) sim += fmaxf(o[d], 0.f) * sd[d];
        sims[c] = sim;
    }
    __syncthreads();
    if (tid < 64) {
        int lane = tid;
        float m = -INFINITY;
        for (int c = lane; c < NC_; c += 64) m = fmaxf(m, sims[c]);
#pragma unroll
        for (int sh = 32; sh; sh >>= 1) m = fmaxf(m, __shfl_xor(m, sh));
        float se = 0.f, v0 = 0.f, v1 = 0.f, v2 = 0.f;
        for (int c = lane; c < NC_; c += 64) {
            float e = expf(sims[c] - m);
            int ix = c / 36, iy = (c / 6) % 6, iz = c % 6;
            se += e;
            v0 += e * (xf[0] + (ix * 0.4f - 1.0f));
            v1 += e * (xf[1] + (iy * 0.4f - 1.0f));
            v2 += e * (xf[2] + (iz * 0.4f - 1.0f));
        }
#pragma unroll
        for (int sh = 32; sh; sh >>= 1) {
            se += __shfl_xor(se, sh);
            v0 += __shfl_xor(v0, sh);
            v1 += __shfl_xor(v1, sh);
            v2 += __shfl_xor(v2, sh);
        }
        if (lane == 0) {
            float inv = 1.0f / se;
            float* oo = out + BB_ * KK_ * CC_ + bk * 3;
            oo[0] = v0 * inv;
            oo[1] = v1 * inv;
            oo[2] = v2 * inv;
        }
    }
}

extern "C" void kernel_launch(void* const* d_in, const int* in_sizes, int n_in,
                              void* d_out, int out_size, void* d_ws, size_t ws_size,
                              hipStream_t stream) {
    const float* src = (const float*)d_in[0];
    const float* tgt = (const float*)d_in[1];
    const float* R   = (const float*)d_in[2];
    const float* t   = (const float*)d_in[3];
    const float* W1  = (const float*)d_in[4];
    const float* b1  = (const float*)d_in[5];
    const float* W2  = (const float*)d_in[6];
    const float* b2  = (const float*)d_in[7];
    const float* Wwl = (const float*)d_in[8];
    const float* bwl = (const float*)d_in[9];
    const float* W3  = (const float*)d_in[10];
    const float* b3  = (const float*)d_in[11];
    const float* W4  = (const float*)d_in[12];
    const float* b4  = (const float*)d_in[13];
    float* ws  = (float*)d_ws;
    float* out = (float*)d_out;

    fe_kernel<<<(2 * BB_ * NN_ + 127) / 128, 128, 0, stream>>>(src, tgt, W1, b1, W2, b2, Wwl, bwl, ws);
    topk_kernel<<<BB_, 1024, 0, stream>>>(src, R, t, ws, out);
    src_group_kernel<<<BB_ * KK_, 1024, 0, stream>>>(W3, b3, W4, b4, ws);
    cand_nn_kernel<<<BB_ * KK_ * 2, 576, 0, stream>>>(ws);
    simvcp_kernel<<<BB_ * KK_, 256, 0, stream>>>(W3, b3, W4, b4, ws, out);
}

// Round 6
// 82.535 us; speedup vs baseline: 4.1629x; 1.0774x over previous
//
#include <hip/hip_runtime.h>
#include <math.h>

// Problem constants
#define BB_ 2      // batch
#define CC_ 6      // channels
#define NN_ 2048   // points
#define KK_ 64     // keypoints
#define NS_ 32     // neighbors
#define DD_ 32     // feat dim
#define NC_ 216    // candidate grid (6^3)
#define HH_ 64     // hidden dim

// Workspace layout (in floats)
#define OFF_SRC_PACK 0                    // B*N float4 = 16384 floats
#define OFF_TGT_PACK 16384                // 16384
#define OFF_SRC_FEAT 32768                // B*N*D = 131072
#define OFF_TGT_FEAT 163840               // 131072
#define OFF_W        294912               // B*N = 4096
#define OFF_CENTERS  299008               // B*K*3 = 384
#define OFF_XFORM    299392               // 384
#define OFF_SRCDFE   299776               // B*K*D = 4096
#define OFF_NNT      303872               // B*K*NC ints = 27648 (dedicated, no alias)

// Order-preserving bijection float -> uint32 (ascending)
__device__ __forceinline__ unsigned sortable_f32(float f) {
    unsigned u = __float_as_uint(f);
    return (u & 0x80000000u) ? ~u : (u | 0x80000000u);
}
__device__ __forceinline__ float unsortable_f32(unsigned s) {
    unsigned u = (s & 0x80000000u) ? (s ^ 0x80000000u) : ~s;
    return __uint_as_float(u);
}

// Full ascending bitonic sort of 64 u64 keys across the 64 lanes of a wave.
__device__ __forceinline__ unsigned long long wave_sort64_asc(unsigned long long key, int lane) {
#pragma unroll
    for (int k = 2; k <= 64; k <<= 1) {
#pragma unroll
        for (int j = k >> 1; j > 0; j >>= 1) {
            unsigned long long other = __shfl_xor(key, j);
            bool lower = (lane & j) == 0;
            bool asc = (lane & k) == 0;
            bool takemin = (lower == asc);
            unsigned long long mn = key < other ? key : other;
            unsigned long long mx = key < other ? other : key;
            key = takemin ? mn : mx;
        }
    }
    return key;
}

// Two ascending sorted 64-runs -> smallest 64 of the union, ascending.
__device__ __forceinline__ unsigned long long merge_keep_min64(unsigned long long a, unsigned long long b, int lane) {
    unsigned long long br = __shfl(b, 63 - lane);
    unsigned long long m = a < br ? a : br;
#pragma unroll
    for (int j = 32; j > 0; j >>= 1) {
        unsigned long long other = __shfl_xor(m, j);
        bool lower = (lane & j) == 0;
        unsigned long long mn = m < other ? m : other;
        unsigned long long mx = m < other ? other : m;
        m = lower ? mn : mx;
    }
    return m;
}

// 1024 threads (16 waves), 2 keys per thread -> runs[0..63] = 64 smallest, ascending.
__device__ __forceinline__ void block_select64_16w(unsigned long long kA, unsigned long long kB,
                                                   unsigned long long* runs, int tid) {
    int w = tid >> 6, lane = tid & 63;
    kA = wave_sort64_asc(kA, lane);
    kB = wave_sort64_asc(kB, lane);
    unsigned long long m = merge_keep_min64(kA, kB, lane);
    runs[w * 64 + lane] = m;
    __syncthreads();
#pragma unroll
    for (int lvl = 8; lvl >= 1; lvl >>= 1) {
        unsigned long long r = 0;
        if (w < lvl) {
            unsigned long long a = runs[w * 64 + lane];
            unsigned long long b = runs[(w + lvl) * 64 + lane];
            r = merge_keep_min64(a, b, lane);
        }
        __syncthreads();
        if (w < lvl) runs[w * 64 + lane] = r;
        __syncthreads();
    }
}

// -------------------- K1: feature extraction (src + tgt) --------------------
__global__ void fe_kernel(const float* __restrict__ src, const float* __restrict__ tgt,
                          const float* __restrict__ W1, const float* __restrict__ b1,
                          const float* __restrict__ W2, const float* __restrict__ b2,
                          const float* __restrict__ Wwl, const float* __restrict__ bwl,
                          float* __restrict__ ws) {
    int tid = blockIdx.x * blockDim.x + threadIdx.x;
    if (tid >= 2 * BB_ * NN_) return;
    int cloud = tid / (BB_ * NN_);
    int r = tid - cloud * BB_ * NN_;
    int b = r / NN_, n = r % NN_;
    const float* pts = cloud ? tgt : src;
    float x[CC_];
#pragma unroll
    for (int c = 0; c < CC_; ++c) x[c] = pts[(b * CC_ + c) * NN_ + n];
    float bb;
    {
#pragma clang fp contract(off)
        bb = (x[0] * x[0] + x[1] * x[1]) + x[2] * x[2];
    }
    float4* pack = (float4*)(ws + (cloud ? OFF_TGT_PACK : OFF_SRC_PACK));
    pack[b * NN_ + n] = make_float4(x[0], x[1], x[2], bb);

    float h[HH_];
#pragma unroll
    for (int t = 0; t < HH_; ++t) {
        float s = b1[t];
#pragma unroll
        for (int c = 0; c < CC_; ++c) s += x[c] * W1[c * HH_ + t];
        h[t] = fmaxf(s, 0.f);
    }
    float* feat = ws + (cloud ? OFF_TGT_FEAT : OFF_SRC_FEAT) + (size_t)(b * NN_ + n) * DD_;
    float wsum = 0.f;
#pragma unroll 4
    for (int d = 0; d < DD_; ++d) {
        float s = b2[d];
#pragma unroll
        for (int t = 0; t < HH_; ++t) s += h[t] * W2[t * DD_ + d];
        s = fmaxf(s, 0.f);
        feat[d] = s;
        wsum += s * Wwl[d];
    }
    if (cloud == 0) (ws + OFF_W)[b * NN_ + n] = wsum + bwl[0];
}

// -------------------- K2: top-K keypoints via wave-bitonic selection --------------------
__global__ void topk_kernel(const float* __restrict__ src, const float* __restrict__ R,
                            const float* __restrict__ t, float* __restrict__ ws,
                            float* __restrict__ out) {
    __shared__ unsigned long long runs[16 * 64];
    int b = blockIdx.x;
    int tid = threadIdx.x, w = tid >> 6, lane = tid & 63;
    const float* wv = ws + OFF_W + b * NN_;
    int jA = w * 128 + lane, jB = jA + 64;
    unsigned long long kA = ((unsigned long long)(~sortable_f32(wv[jA])) << 32) | (unsigned)jA;
    unsigned long long kB = ((unsigned long long)(~sortable_f32(wv[jB])) << 32) | (unsigned)jB;
    block_select64_16w(kA, kB, runs, tid);
    if (tid < KK_) {
        int bi = (int)(runs[tid] & 0xFFFFFFFFu);
        float c3[3];
#pragma unroll
        for (int c = 0; c < CC_; ++c) {
            float v = src[(b * CC_ + c) * NN_ + bi];
            out[(b * KK_ + tid) * CC_ + c] = v;
            if (c < 3) c3[c] = v;
        }
        float* cen = ws + OFF_CENTERS + (b * KK_ + tid) * 3;
        cen[0] = c3[0]; cen[1] = c3[1]; cen[2] = c3[2];
        float* xf = ws + OFF_XFORM + (b * KK_ + tid) * 3;
#pragma unroll
        for (int i = 0; i < 3; ++i) {
#pragma clang fp contract(off)
            xf[i] = ((R[i * 3 + 0] * c3[0] + R[i * 3 + 1] * c3[1]) + R[i * 3 + 2] * c3[2]) + t[i];
        }
    }
}

// -------------------- K3: fused middle stage, 384 blocks x 576 threads ----------
// blocks 0..255   : candidate NN search (2 blocks per bk, 18 xy-groups each)
// blocks 256..383 : src neighbor grouping + dfe + max (1 block per bk, 9 waves)
__global__ __launch_bounds__(576) void mid_kernel(const float* __restrict__ W3, const float* __restrict__ b3,
                                                  const float* __restrict__ W4, const float* __restrict__ b4,
                                                  float* __restrict__ ws) {
    __shared__ union U {
        float4 pk[NN_];                                      // cand role: 32 KB
        struct {
            unsigned long long runs[8 * 64];                 // src role: 4 KB
            float hs[NS_][HH_];                              // 8 KB
            float outs[NS_][DD_];                            // 4 KB
        } s;
    } u;
    int blk = blockIdx.x;
    int tid = threadIdx.x;                                   // 0..575
    if (blk < 2 * BB_ * KK_) {
        // ---------------- candidate NN role ----------------
        int bk = blk >> 1;
        int half = blk & 1;
        int b = bk / KK_;
        const float4* pack = (const float4*)(ws + OFF_TGT_PACK) + b * NN_;
        for (int j = tid; j < NN_; j += 576) {
            u.pk[j ^ ((j >> 6) & 7)] = pack[j];              // XOR-swizzled slots
        }
        const float* xf = ws + OFF_XFORM + bk * 3;
        float x0 = xf[0], x1 = xf[1], x2 = xf[2];
        __syncthreads();

        int lg = tid >> 5;                                   // local group 0..17
        int chunk = tid & 31;
        int grp = half * 18 + lg;                            // 0..35 = ix*6+iy
        int ix = grp / 6, iy = grp % 6;
        float cx = x0 + (ix * 0.4f - 1.0f);
        float cy = x1 + (iy * 0.4f - 1.0f);
        float cxy2;
        {
#pragma clang fp contract(off)
            cxy2 = cx * cx + cy * cy;
        }
        float m2x = -2.0f * cx, m2y = -2.0f * cy;
        float aaz[6], m2z[6];
#pragma unroll
        for (int z = 0; z < 6; ++z) {
            float cz = x2 + (z * 0.4f - 1.0f);
            {
#pragma clang fp contract(off)
                aaz[z] = cxy2 + cz * cz;
            }
            m2z[z] = -2.0f * cz;
        }
        float bv[6];
        int bi[6];
#pragma unroll
        for (int z = 0; z < 6; ++z) { bv[z] = INFINITY; bi[z] = 0; }
        int base = chunk * 64;
        int sw = chunk & 7;
        for (int i = 0; i < 64; ++i) {
            int j = base + i;                                // ascending j (first-idx ties)
            float4 p = u.pk[base + (i ^ sw)];                // slot(j) for j=base+i
            float txy;
            {
#pragma clang fp contract(off)
                txy = m2x * p.x + m2y * p.y;
            }
#pragma unroll
            for (int z = 0; z < 6; ++z) {
                float d2;
                {
#pragma clang fp contract(off)
                    d2 = (aaz[z] + p.w) + (txy + m2z[z] * p.z);
                }
                if (d2 < bv[z]) { bv[z] = d2; bi[z] = j; }
            }
        }
        int* nnt = (int*)ws + OFF_NNT + bk * NC_ + grp * 6;
#pragma unroll
        for (int z = 0; z < 6; ++z) {
            unsigned long long key = ((unsigned long long)sortable_f32(bv[z]) << 32) | (unsigned)bi[z];
#pragma unroll
            for (int m = 1; m <= 16; m <<= 1) {
                unsigned long long other = __shfl_xor(key, m);
                key = other < key ? other : key;
            }
            if (chunk == 0) nnt[z] = (int)(key & 0xFFFFFFFFu);
        }
    } else {
        // ---------------- src grouping role ----------------
        int bk = blk - 2 * BB_ * KK_;
        int b = bk / KK_;
        int w = tid >> 6, lane = tid & 63;
        const float* cen = ws + OFF_CENTERS + bk * 3;
        float c0 = cen[0], c1 = cen[1], c2 = cen[2];
        float aa;
        {
#pragma clang fp contract(off)
            aa = (c0 * c0 + c1 * c1) + c2 * c2;
        }
        float m2x = -2.0f * c0, m2y = -2.0f * c1, m2z = -2.0f * c2;
        const float4* pack = (const float4*)(ws + OFF_SRC_PACK) + b * NN_;
        // 9 waves: waves 0..7 each cover 256 points (4 keys/thread)
        if (w < 8) {
            unsigned long long k4[4];
#pragma unroll
            for (int q = 0; q < 4; ++q) {
                int j = w * 256 + q * 64 + lane;
                float4 p = pack[j];
                float d2;
                {
#pragma clang fp contract(off)
                    d2 = (aa + p.w) + ((m2x * p.x + m2y * p.y) + m2z * p.z);
                }
                k4[q] = ((unsigned long long)sortable_f32(d2) << 32) | (unsigned)j;
            }
            unsigned long long m1 = merge_keep_min64(wave_sort64_asc(k4[0], lane),
                                                     wave_sort64_asc(k4[1], lane), lane);
            unsigned long long m2 = merge_keep_min64(wave_sort64_asc(k4[2], lane),
                                                     wave_sort64_asc(k4[3], lane), lane);
            u.s.runs[w * 64 + lane] = merge_keep_min64(m1, m2, lane);
        }
        __syncthreads();
#pragma unroll
        for (int lvl = 4; lvl >= 1; lvl >>= 1) {
            unsigned long long r = 0;
            if (w < lvl) {
                r = merge_keep_min64(u.s.runs[w * 64 + lane], u.s.runs[(w + lvl) * 64 + lane], lane);
            }
            __syncthreads();
            if (w < lvl) u.s.runs[w * 64 + lane] = r;
            __syncthreads();
        }
        // MLP layer 1: waves 0..7, 4 neighbors each
        const float* feats = ws + OFF_SRC_FEAT + (size_t)b * NN_ * DD_;
        unsigned long long key0 = u.s.runs[0];
        if (w < 8) {
#pragma unroll
            for (int ss = 0; ss < 4; ++ss) {
                int s = w * 4 + ss;
                unsigned long long key = u.s.runs[s];
                float dd = unsortable_f32((unsigned)(key >> 32));
                int j = (dd <= 1.0f) ? (int)(key & 0xFFFFFFFFu) : (int)(key0 & 0xFFFFFFFFu);  // R^2=1
                float4 p = pack[j];
                float r0 = p.x - c0, r1 = p.y - c1, r2 = p.z - c2;
                const float* f = feats + (size_t)j * DD_;
                float acc = b3[lane] + r0 * W3[0 * HH_ + lane] + r1 * W3[1 * HH_ + lane] + r2 * W3[2 * HH_ + lane];
#pragma unroll 8
                for (int d = 0; d < DD_; ++d) acc += f[d] * W3[(3 + d) * HH_ + lane];
                u.s.hs[s][lane] = fmaxf(acc, 0.f);
            }
        }
        __syncthreads();
        // MLP layer 2: 32 neighbors x 32 outputs = 1024 slots over 576 threads
        for (int idx = tid; idx < NS_ * DD_; idx += 576) {
            int s2 = idx >> 5, di = idx & 31;
            float o = b4[di];
#pragma unroll 8
            for (int t2 = 0; t2 < HH_; ++t2) o += u.s.hs[s2][t2] * W4[t2 * DD_ + di];
            u.s.outs[s2][di] = fmaxf(o, 0.f);
        }
        __syncthreads();
        if (tid < DD_) {
            float m = -INFINITY;
#pragma unroll 8
            for (int s = 0; s < NS_; ++s) m = fmaxf(m, u.s.outs[s][tid]);
            (ws + OFF_SRCDFE)[bk * DD_ + tid] = m;
        }
    }
}

// -------------------- K4: per-candidate MLP + sim + softmax + vcp (fused) ----
__global__ void simvcp_kernel(const float* __restrict__ W3, const float* __restrict__ b3,
                              const float* __restrict__ W4, const float* __restrict__ b4,
                              float* __restrict__ ws, float* __restrict__ out) {
    __shared__ float sims[NC_];
    int bk = blockIdx.x;
    int b = bk / KK_;
    int tid = threadIdx.x;
    const float* xf = ws + OFF_XFORM + bk * 3;
    if (tid < NC_) {
        int c = tid;
        int ix = c / 36, iy = (c / 6) % 6, iz = c % 6;
        float cx = xf[0] + (ix * 0.4f - 1.0f);
        float cy = xf[1] + (iy * 0.4f - 1.0f);
        float cz = xf[2] + (iz * 0.4f - 1.0f);
        int bi = ((const int*)ws)[OFF_NNT + bk * NC_ + c];
        float4 p = ((const float4*)(ws + OFF_TGT_PACK))[b * NN_ + bi];
        float x[3 + DD_];
        x[0] = p.x - cx; x[1] = p.y - cy; x[2] = p.z - cz;
        const float* f = ws + OFF_TGT_FEAT + ((size_t)b * NN_ + bi) * DD_;
#pragma unroll
        for (int d = 0; d < DD_; ++d) x[3 + d] = f[d];
        float o[DD_];
#pragma unroll
        for (int d = 0; d < DD_; ++d) o[d] = b4[d];
        for (int t = 0; t < HH_; ++t) {
            float acc = b3[t];
#pragma unroll
            for (int cc = 0; cc < 3 + DD_; ++cc) acc += x[cc] * W3[cc * HH_ + t];
            float ht = fmaxf(acc, 0.f);
#pragma unroll
            for (int d = 0; d < DD_; ++d) o[d] += ht * W4[t * DD_ + d];
        }
        const float* sd = ws + OFF_SRCDFE + bk * DD_;
        float sim = 0.f;
#pragma unroll
        for (int d = 0; d < DD_; ++d) sim += fmaxf(o[d], 0.f) * sd[d];
        sims[c] = sim;
    }
    __syncthreads();
    if (tid < 64) {
        int lane = tid;
        float m = -INFINITY;
        for (int c = lane; c < NC_; c += 64) m = fmaxf(m, sims[c]);
#pragma unroll
        for (int sh = 32; sh; sh >>= 1) m = fmaxf(m, __shfl_xor(m, sh));
        float se = 0.f, v0 = 0.f, v1 = 0.f, v2 = 0.f;
        for (int c = lane; c < NC_; c += 64) {
            float e = expf(sims[c] - m);
            int ix = c / 36, iy = (c / 6) % 6, iz = c % 6;
            se += e;
            v0 += e * (xf[0] + (ix * 0.4f - 1.0f));
            v1 += e * (xf[1] + (iy * 0.4f - 1.0f));
            v2 += e * (xf[2] + (iz * 0.4f - 1.0f));
        }
#pragma unroll
        for (int sh = 32; sh; sh >>= 1) {
            se += __shfl_xor(se, sh);
            v0 += __shfl_xor(v0, sh);
            v1 += __shfl_xor(v1, sh);
            v2 += __shfl_xor(v2, sh);
        }
        if (lane == 0) {
            float inv = 1.0f / se;
            float* oo = out + BB_ * KK_ * CC_ + bk * 3;
            oo[0] = v0 * inv;
            oo[1] = v1 * inv;
            oo[2] = v2 * inv;
        }
    }
}

extern "C" void kernel_launch(void* const* d_in, const int* in_sizes, int n_in,
                              void* d_out, int out_size, void* d_ws, size_t ws_size,
                              hipStream_t stream) {
    const float* src = (const float*)d_in[0];
    const float* tgt = (const float*)d_in[1];
    const float* R   = (const float*)d_in[2];
    const float* t   = (const float*)d_in[3];
    const float* W1  = (const float*)d_in[4];
    const float* b1  = (const float*)d_in[5];
    const float* W2  = (const float*)d_in[6];
    const float* b2  = (const float*)d_in[7];
    const float* Wwl = (const float*)d_in[8];
    const float* bwl = (const float*)d_in[9];
    const float* W3  = (const float*)d_in[10];
    const float* b3  = (const float*)d_in[11];
    const float* W4  = (const float*)d_in[12];
    const float* b4  = (const float*)d_in[13];
    float* ws  = (float*)d_ws;
    float* out = (float*)d_out;

    fe_kernel<<<(2 * BB_ * NN_ + 127) / 128, 128, 0, stream>>>(src, tgt, W1, b1, W2, b2, Wwl, bwl, ws);
    topk_kernel<<<BB_, 1024, 0, stream>>>(src, R, t, ws, out);
    mid_kernel<<<2 * BB_ * KK_ + BB_ * KK_, 576, 0, stream>>>(W3, b3, W4, b4, ws);
    simvcp_kernel<<<BB_ * KK_, 256, 0, stream>>>(W3, b3, W4, b4, ws, out);
}